// Round 3
// baseline (9610.216 us; speedup 1.0000x reference)
//
#include <hip/hip_runtime.h>
#include <hip/hip_bf16.h>
#include <math.h>

#define BB   32
#define SS   128
#define DD   64
#define HH   4
#define HDD  16
#define HTT  256
#define TEE  1024
#define NTHR 512
#define KVSTR 68            // K/V row stride in scratch (64+4)
#define VOFF  (SS * KVSTR)  // V region offset inside scratch (8704 floats)
#define MSTR 132            // mlp half row stride (128+4)
#define STEPF 0.1f

// ---------------------------------------------------------------------------
// Kernel 1: precompute temb[t][d] for all t (shared across batches).
// temb = silu(te @ t_w1 + t_b1) @ t_w2 + t_b2,  te = [cos(t*f), sin(t*f)]
// ---------------------------------------------------------------------------
__global__ void temb_precompute(const int* __restrict__ nloops_p,
                                const float* __restrict__ t_w1,
                                const float* __restrict__ t_b1,
                                const float* __restrict__ t_w2,
                                const float* __restrict__ t_b2,
                                float* __restrict__ tembBuf) {
    const int t = blockIdx.x;
    const int nl = nloops_p[0];
    if (t >= nl) return;

    __shared__ float te_s[HTT];
    __shared__ float h1[TEE];
    const int tid = threadIdx.x;
    const float tf = (float)t;

    {
        int fi = (tid < 128) ? tid : (tid - 128);
        float freq = expf(-9.210340371976184f * (float)fi * (1.0f / 128.0f));
        float arg = tf * freq;
        te_s[tid] = (tid < 128) ? cosf(arg) : sinf(arg);
    }
    __syncthreads();

    for (int j = tid; j < TEE; j += 256) {
        float acc = t_b1[j];
        for (int i = 0; i < HTT; ++i) {
            acc = fmaf(te_s[i], t_w1[i * TEE + j], acc);
        }
        h1[j] = acc / (1.0f + expf(-acc));   // silu
    }
    __syncthreads();

    {
        const int d = tid >> 2;        // 0..63
        const int part = tid & 3;      // 0..3
        float acc = 0.0f;
        for (int j = part; j < TEE; j += 4) {
            acc = fmaf(h1[j], t_w2[j * DD + d], acc);
        }
        acc += __shfl_xor(acc, 1);
        acc += __shfl_xor(acc, 2);
        if (part == 0) tembBuf[t * DD + d] = acc + t_b2[d];
    }
}

// ---------------------------------------------------------------------------
// GELU (tanh approximation, matches jax.nn.gelu approximate=True)
// ---------------------------------------------------------------------------
__device__ __forceinline__ float gelu_tanh(float u) {
    float z = 0.7978845608028654f * (u + 0.044715f * u * u * u);
    float e = __expf(2.0f * z);
    float th = 1.0f - 2.0f / (e + 1.0f);   // tanh(z), inf-safe
    return 0.5f * u * (1.0f + th);
}

// ---------------------------------------------------------------------------
// Kernel 2: whole looped transformer, one block per batch.
// LDS: xs 32KB (state) + hs 32KB (LN-out / Q / attn-out)
//      + scratch 68KB (K,V / mlp-half)  = 132KB total
// ---------------------------------------------------------------------------
__global__ __launch_bounds__(NTHR)
void looped_tf(const int* __restrict__ idx,
               const int* __restrict__ nloops_p,
               const float* __restrict__ wte,
               const float* __restrict__ wpe,
               const float* __restrict__ ln1_g, const float* __restrict__ ln1_b,
               const float* __restrict__ w_qkv, const float* __restrict__ b_qkv,
               const float* __restrict__ w_o,   const float* __restrict__ b_o,
               const float* __restrict__ ln2_g, const float* __restrict__ ln2_b,
               const float* __restrict__ w_fc,  const float* __restrict__ b_fc,
               const float* __restrict__ w_pr,  const float* __restrict__ b_pr,
               const float* __restrict__ lnf_g, const float* __restrict__ lnf_b,
               const float* __restrict__ tembBuf,
               float* __restrict__ out) {
    __shared__ float xs[SS * DD];          // 32 KB state
    __shared__ float hs[SS * DD];          // 32 KB LN-out / Q / attn-out
    __shared__ float scratch[2 * SS * KVSTR]; // 68 KB: K,V or mlp-half

    const int b = blockIdx.x;
    const int tid = threadIdx.x;
    const int nl = nloops_p[0];

    // ------ init: x = wte[idx] + wpe ------
    for (int i = tid; i < SS * DD; i += NTHR) {
        int s = i >> 6;
        xs[i] = wte[idx[b * SS + s] * DD + (i & 63)] + wpe[i];
    }
    __syncthreads();

    const int tok4 = tid >> 2, sub4 = tid & 3;   // LN mapping: 4 lanes/token

    // LayerNorm(xs) -> dst (row stride 64), fused gamma/beta
    auto layer_norm_to = [&](const float* __restrict__ g,
                             const float* __restrict__ be,
                             float* __restrict__ dst) {
        float v[16];
        const float* xp = xs + tok4 * DD + sub4 * 16;
        float s1 = 0.f, s2 = 0.f;
#pragma unroll
        for (int r = 0; r < 4; ++r) {
            float4 f = *(const float4*)(xp + 4 * r);
            v[4*r+0] = f.x; v[4*r+1] = f.y; v[4*r+2] = f.z; v[4*r+3] = f.w;
            s1 += f.x + f.y + f.z + f.w;
            s2 += f.x*f.x + f.y*f.y + f.z*f.z + f.w*f.w;
        }
        s1 += __shfl_xor(s1, 1); s2 += __shfl_xor(s2, 1);
        s1 += __shfl_xor(s1, 2); s2 += __shfl_xor(s2, 2);
        float mu = s1 * (1.0f / 64.0f);
        float var = s2 * (1.0f / 64.0f) - mu * mu;
        float rs = rsqrtf(var + 1e-5f);
#pragma unroll
        for (int i = 0; i < 16; ++i) {
            int d2 = sub4 * 16 + i;
            dst[tok4 * DD + d2] = (v[i] - mu) * rs * g[d2] + be[d2];
        }
    };

    for (int t = 0; t < nl; ++t) {
        // ---- A: x += temb[t] ----
        for (int i = tid; i < SS * DD; i += NTHR)
            xs[i] += tembBuf[t * DD + (i & 63)];
        __syncthreads();

        // ---- B: h = LN1(x) -> hs ----
        layer_norm_to(ln1_g, ln1_b, hs);
        __syncthreads();

        // ---- C: qkv = h @ w_qkv + b_qkv  (128x64 @ 64x192) ----
        // Q -> hs (overwrites h after barrier), K,V -> scratch
        {
            const int jg = tid & 31, tg = tid >> 5;   // 32 col-groups x 16 tok-groups
            const int j0 = jg * 6, t0 = tg * 8;
            float acc[8][6];
#pragma unroll
            for (int a = 0; a < 8; ++a)
#pragma unroll
                for (int c = 0; c < 6; ++c) acc[a][c] = 0.f;
            for (int d = 0; d < DD; ++d) {
                const float* wp = w_qkv + d * 192 + j0;
                float2 w01 = *(const float2*)(wp + 0);
                float2 w23 = *(const float2*)(wp + 2);
                float2 w45 = *(const float2*)(wp + 4);
                float w[6] = {w01.x, w01.y, w23.x, w23.y, w45.x, w45.y};
#pragma unroll
                for (int a = 0; a < 8; ++a) {
                    float hv = hs[(t0 + a) * DD + d];
#pragma unroll
                    for (int c = 0; c < 6; ++c)
                        acc[a][c] = fmaf(hv, w[c], acc[a][c]);
                }
            }
            __syncthreads();   // all reads of h done before Q overwrites hs
#pragma unroll
            for (int a = 0; a < 8; ++a) {
#pragma unroll
                for (int c = 0; c < 6; ++c) {
                    int col = j0 + c;
                    float v = acc[a][c] + b_qkv[col];
                    if (col < 64)
                        hs[(t0 + a) * DD + col] = v;                       // Q
                    else if (col < 128)
                        scratch[(t0 + a) * KVSTR + (col - 64)] = v;        // K
                    else
                        scratch[VOFF + (t0 + a) * KVSTR + (col - 128)] = v; // V
                }
            }
        }
        __syncthreads();

        // ---- D: causal attention, one (q-row, head) per thread ----
        {
            const int q = tid >> 2, h = tid & 3;
            float qv[16];
            const float* qp = hs + q * DD + h * HDD;
#pragma unroll
            for (int r = 0; r < 4; ++r) {
                float4 f = *(const float4*)(qp + 4 * r);
                qv[4*r+0] = f.x; qv[4*r+1] = f.y; qv[4*r+2] = f.z; qv[4*r+3] = f.w;
            }
            float mrun = -3.0e38f, l = 0.f;
            float acc[16];
#pragma unroll
            for (int i = 0; i < 16; ++i) acc[i] = 0.f;
            for (int kk = 0; kk <= q; ++kk) {
                const float* kp = scratch + kk * KVSTR + h * HDD;
                const float* vp = scratch + VOFF + kk * KVSTR + h * HDD;
                float s = 0.f;
                float vv[16];
#pragma unroll
                for (int r = 0; r < 4; ++r) {
                    float4 kf = *(const float4*)(kp + 4 * r);
                    float4 vf = *(const float4*)(vp + 4 * r);
                    s = fmaf(qv[4*r+0], kf.x, s);
                    s = fmaf(qv[4*r+1], kf.y, s);
                    s = fmaf(qv[4*r+2], kf.z, s);
                    s = fmaf(qv[4*r+3], kf.w, s);
                    vv[4*r+0] = vf.x; vv[4*r+1] = vf.y; vv[4*r+2] = vf.z; vv[4*r+3] = vf.w;
                }
                s *= 0.25f;   // 1/sqrt(16)
                float mn = fmaxf(mrun, s);
                float corr = __expf(mrun - mn);  // first iter: exp(-inf)=0
                float p = __expf(s - mn);
                l = fmaf(l, corr, p);
#pragma unroll
                for (int i = 0; i < 16; ++i)
                    acc[i] = fmaf(acc[i], corr, p * vv[i]);
                mrun = mn;
            }
            float inv = 1.0f / l;
            // each thread overwrites exactly the hs slice it alone read (its Q)
#pragma unroll
            for (int i = 0; i < 16; ++i)
                hs[q * DD + h * HDD + i] = acc[i] * inv;
        }
        __syncthreads();

        // ---- E: x += STEP * (a @ w_o + b_o) ----
        {
            const int dg = tid & 15, tg = tid >> 4;  // 16 col-groups x 32 tok-groups
            const int d0 = dg * 4, t0 = tg * 4;
            float acc[4][4];
#pragma unroll
            for (int a = 0; a < 4; ++a)
#pragma unroll
                for (int c = 0; c < 4; ++c) acc[a][c] = 0.f;
            for (int dd = 0; dd < DD; ++dd) {
                float4 w = *(const float4*)(w_o + dd * DD + d0);
#pragma unroll
                for (int a = 0; a < 4; ++a) {
                    float av = hs[(t0 + a) * DD + dd];
                    acc[a][0] = fmaf(av, w.x, acc[a][0]);
                    acc[a][1] = fmaf(av, w.y, acc[a][1]);
                    acc[a][2] = fmaf(av, w.z, acc[a][2]);
                    acc[a][3] = fmaf(av, w.w, acc[a][3]);
                }
            }
            float4 bo = *(const float4*)(b_o + d0);
#pragma unroll
            for (int a = 0; a < 4; ++a) {
                xs[(t0+a)*DD + d0+0] += STEPF * (acc[a][0] + bo.x);
                xs[(t0+a)*DD + d0+1] += STEPF * (acc[a][1] + bo.y);
                xs[(t0+a)*DD + d0+2] += STEPF * (acc[a][2] + bo.z);
                xs[(t0+a)*DD + d0+3] += STEPF * (acc[a][3] + bo.w);
            }
        }
        __syncthreads();

        // ---- F: h2 = LN2(x) -> hs ----
        layer_norm_to(ln2_g, ln2_b, hs);
        __syncthreads();

        // ---- G/H: MLP (two 128-col halves of fc share scratch) ----
        {
            const int dgP = tid & 15, tgP = tid >> 4;
            const int d0P = dgP * 4, t0P = tgP * 4;
            float pracc[4][4];
#pragma unroll
            for (int a = 0; a < 4; ++a)
#pragma unroll
                for (int c = 0; c < 4; ++c) pracc[a][c] = 0.f;

#pragma unroll
            for (int hf = 0; hf < 2; ++hf) {
                {
                    const int jg = tid & 31, tg = tid >> 5;
                    const int j0 = jg * 4, t0 = tg * 8;
                    float acc[8][4];
#pragma unroll
                    for (int a = 0; a < 8; ++a)
#pragma unroll
                        for (int c = 0; c < 4; ++c) acc[a][c] = 0.f;
                    for (int d = 0; d < DD; ++d) {
                        float4 w = *(const float4*)(w_fc + d * 256 + hf * 128 + j0);
#pragma unroll
                        for (int a = 0; a < 8; ++a) {
                            float hv = hs[(t0 + a) * DD + d];
                            acc[a][0] = fmaf(hv, w.x, acc[a][0]);
                            acc[a][1] = fmaf(hv, w.y, acc[a][1]);
                            acc[a][2] = fmaf(hv, w.z, acc[a][2]);
                            acc[a][3] = fmaf(hv, w.w, acc[a][3]);
                        }
                    }
                    float4 bf = *(const float4*)(b_fc + hf * 128 + j0);
#pragma unroll
                    for (int a = 0; a < 8; ++a) {
                        scratch[(t0+a)*MSTR + j0+0] = gelu_tanh(acc[a][0] + bf.x);
                        scratch[(t0+a)*MSTR + j0+1] = gelu_tanh(acc[a][1] + bf.y);
                        scratch[(t0+a)*MSTR + j0+2] = gelu_tanh(acc[a][2] + bf.z);
                        scratch[(t0+a)*MSTR + j0+3] = gelu_tanh(acc[a][3] + bf.w);
                    }
                }
                __syncthreads();
                for (int j = 0; j < 128; ++j) {
                    float4 w = *(const float4*)(w_pr + (hf * 128 + j) * DD + d0P);
#pragma unroll
                    for (int a = 0; a < 4; ++a) {
                        float mv = scratch[(t0P + a) * MSTR + j];
                        pracc[a][0] = fmaf(mv, w.x, pracc[a][0]);
                        pracc[a][1] = fmaf(mv, w.y, pracc[a][1]);
                        pracc[a][2] = fmaf(mv, w.z, pracc[a][2]);
                        pracc[a][3] = fmaf(mv, w.w, pracc[a][3]);
                    }
                }
                __syncthreads();   // before next half overwrites scratch
            }
            float4 bp = *(const float4*)(b_pr + d0P);
#pragma unroll
            for (int a = 0; a < 4; ++a) {
                xs[(t0P+a)*DD + d0P+0] += STEPF * (pracc[a][0] + bp.x);
                xs[(t0P+a)*DD + d0P+1] += STEPF * (pracc[a][1] + bp.y);
                xs[(t0P+a)*DD + d0P+2] += STEPF * (pracc[a][2] + bp.z);
                xs[(t0P+a)*DD + d0P+3] += STEPF * (pracc[a][3] + bp.w);
            }
        }
        __syncthreads();   // xs stable before next iteration
    }

    // ---- final LN -> out ----
    layer_norm_to(lnf_g, lnf_b, out + b * SS * DD);
}

// ---------------------------------------------------------------------------
extern "C" void kernel_launch(void* const* d_in, const int* in_sizes, int n_in,
                              void* d_out, int out_size, void* d_ws, size_t ws_size,
                              hipStream_t stream) {
    const int*   idx    = (const int*)  d_in[0];
    const int*   nloops = (const int*)  d_in[1];
    const float* wte    = (const float*)d_in[2];
    const float* wpe    = (const float*)d_in[3];
    const float* t_w1   = (const float*)d_in[4];
    const float* t_b1   = (const float*)d_in[5];
    const float* t_w2   = (const float*)d_in[6];
    const float* t_b2   = (const float*)d_in[7];
    const float* ln1_g  = (const float*)d_in[8];
    const float* ln1_b  = (const float*)d_in[9];
    const float* w_qkv  = (const float*)d_in[10];
    const float* b_qkv  = (const float*)d_in[11];
    const float* w_o    = (const float*)d_in[12];
    const float* b_o    = (const float*)d_in[13];
    const float* ln2_g  = (const float*)d_in[14];
    const float* ln2_b  = (const float*)d_in[15];
    const float* w_fc   = (const float*)d_in[16];
    const float* b_fc   = (const float*)d_in[17];
    const float* w_pr   = (const float*)d_in[18];
    const float* b_pr   = (const float*)d_in[19];
    const float* lnf_g  = (const float*)d_in[20];
    const float* lnf_b  = (const float*)d_in[21];

    float* tembBuf = (float*)d_ws;   // 128*64 floats used

    temb_precompute<<<128, 256, 0, stream>>>(nloops, t_w1, t_b1, t_w2, t_b2, tembBuf);
    looped_tf<<<BB, NTHR, 0, stream>>>(idx, nloops, wte, wpe, ln1_g, ln1_b,
                                       w_qkv, b_qkv, w_o, b_o, ln2_g, ln2_b,
                                       w_fc, b_fc, w_pr, b_pr, lnf_g, lnf_b,
                                       tembBuf, (float*)d_out);
}